// Round 3
// baseline (8113.440 us; speedup 1.0000x reference)
//
#include <hip/hip_runtime.h>
#include <hip/hip_bf16.h>

#define H 32
#define DOUT 16
#define EIN_DIM 68

__device__ __forceinline__ float silu(float v) {
    return v * __builtin_amdgcn_rcpf(1.0f + __expf(-v));
}

// ---- init: x = pos@projW.T, h = attrs@embW.T + b; zero accumulators --------
__global__ __launch_bounds__(256) void init_nodes(
    const float* __restrict__ node_attrs, const float* __restrict__ positions,
    const float* __restrict__ projW, const float* __restrict__ embW,
    const float* __restrict__ embB,
    float* __restrict__ x, float* __restrict__ h,
    float* __restrict__ xsum, float* __restrict__ cnt, float* __restrict__ magg,
    int N)
{
    int n = blockIdx.x * blockDim.x + threadIdx.x;
    if (n >= N) return;
    float p0 = positions[3*n+0];
    float p1 = positions[3*n+1];
    float p2 = positions[3*n+2];
    #pragma unroll
    for (int i = 0; i < DOUT; ++i) {
        x[n*DOUT+i] = projW[i*3+0]*p0 + projW[i*3+1]*p1 + projW[i*3+2]*p2;
        xsum[n*DOUT+i] = 0.0f;
    }
    float a0 = node_attrs[3*n+0];
    float a1 = node_attrs[3*n+1];
    float a2 = node_attrs[3*n+2];
    #pragma unroll
    for (int j = 0; j < H; ++j) {
        h[n*H+j] = embB[j] + embW[j*3+0]*a0 + embW[j*3+1]*a1 + embW[j*3+2]*a2;
        magg[n*H+j] = 0.0f;
    }
    cnt[n] = 0.0f;
}

// ---- edge kernel: one thread per edge --------------------------------------
__global__ __launch_bounds__(256) void edge_kernel(
    const int* __restrict__ row, const int* __restrict__ col,
    const float* __restrict__ positions,
    const float* __restrict__ x, const float* __restrict__ h,
    const float* __restrict__ W1, const float* __restrict__ b1,
    const float* __restrict__ W2, const float* __restrict__ b2,
    const float* __restrict__ cW1, const float* __restrict__ cb1,
    const float* __restrict__ cW2,
    float* __restrict__ xsum, float* __restrict__ cnt, float* __restrict__ magg,
    int E)
{
    // [k][tid] layout: lanes stride-1 -> conflict-free; no cross-thread use -> no sync
    __shared__ float mbuf[H][256];
    int e = blockIdx.x * blockDim.x + threadIdx.x;
    if (e >= E) return;
    int t = threadIdx.x;
    int r = row[e], c = col[e];

    float cd[DOUT];
    {
        const float4* xr = (const float4*)(x + (size_t)r * DOUT);
        const float4* xc = (const float4*)(x + (size_t)c * DOUT);
        #pragma unroll
        for (int q = 0; q < DOUT/4; ++q) {
            float4 a = xr[q], b = xc[q];
            cd[4*q+0] = a.x - b.x; cd[4*q+1] = a.y - b.y;
            cd[4*q+2] = a.z - b.z; cd[4*q+3] = a.w - b.w;
        }
    }
    float radial = 0.0f;
    #pragma unroll
    for (int i = 0; i < DOUT; ++i) radial += cd[i] * cd[i];

    float ein[EIN_DIM];
    {
        const float4* hr = (const float4*)(h + (size_t)r * H);
        const float4* hc = (const float4*)(h + (size_t)c * H);
        #pragma unroll
        for (int q = 0; q < H/4; ++q) {
            float4 v = hr[q];
            ein[4*q+0]=v.x; ein[4*q+1]=v.y; ein[4*q+2]=v.z; ein[4*q+3]=v.w;
        }
        #pragma unroll
        for (int q = 0; q < H/4; ++q) {
            float4 v = hc[q];
            ein[H+4*q+0]=v.x; ein[H+4*q+1]=v.y; ein[H+4*q+2]=v.z; ein[H+4*q+3]=v.w;
        }
    }
    ein[64] = radial;
    #pragma unroll
    for (int i = 0; i < 3; ++i)
        ein[65+i] = positions[3*r+i] - positions[3*c+i];

    // edge MLP layer 1: 68 -> 32, silu (weights via uniform s_load)
    #pragma unroll 1
    for (int j = 0; j < H; ++j) {
        float a = b1[j];
        #pragma unroll
        for (int k = 0; k < EIN_DIM; ++k) a += ein[k] * W1[j*EIN_DIM+k];
        mbuf[j][t] = silu(a);
    }
    float m1[H];
    #pragma unroll
    for (int k = 0; k < H; ++k) m1[k] = mbuf[k][t];

    // edge MLP layer 2: 32 -> 32, silu; scatter m_agg
    #pragma unroll 1
    for (int j = 0; j < H; ++j) {
        float a = b2[j];
        #pragma unroll
        for (int k = 0; k < H; ++k) a += m1[k] * W2[j*H+k];
        float v = silu(a);
        mbuf[j][t] = v;
        unsafeAtomicAdd(&magg[(size_t)r*H + j], v);
    }
    float m2[H];
    #pragma unroll
    for (int k = 0; k < H; ++k) m2[k] = mbuf[k][t];

    // coord MLP: 32 -> 32 silu -> 1
    float cm = 0.0f;
    #pragma unroll 1
    for (int j = 0; j < H; ++j) {
        float a = cb1[j];
        #pragma unroll
        for (int k = 0; k < H; ++k) a += m2[k] * cW1[j*H+k];
        cm += silu(a) * cW2[j];
    }

    #pragma unroll
    for (int i = 0; i < DOUT; ++i)
        unsafeAtomicAdd(&xsum[(size_t)r*DOUT + i], cd[i] * cm);
    unsafeAtomicAdd(&cnt[r], 1.0f);
}

// ---- node update: x += xsum/max(cnt,1); h += MLP([h, m_agg]); zero accums --
__global__ __launch_bounds__(256) void node_kernel(
    const float* __restrict__ W1, const float* __restrict__ b1,
    const float* __restrict__ W2, const float* __restrict__ b2,
    float* __restrict__ x, float* __restrict__ h,
    float* __restrict__ xsum, float* __restrict__ cnt, float* __restrict__ magg,
    int N)
{
    __shared__ float sbuf[H][256];
    int n = blockIdx.x * blockDim.x + threadIdx.x;
    if (n >= N) return;
    int t = threadIdx.x;

    float cdiv = __builtin_amdgcn_rcpf(fmaxf(cnt[n], 1.0f));
    cnt[n] = 0.0f;
    #pragma unroll
    for (int i = 0; i < DOUT; ++i) {
        x[(size_t)n*DOUT+i] += xsum[(size_t)n*DOUT+i] * cdiv;
        xsum[(size_t)n*DOUT+i] = 0.0f;
    }

    float nin[2*H];
    #pragma unroll
    for (int k = 0; k < H; ++k) nin[k] = h[(size_t)n*H+k];
    #pragma unroll
    for (int k = 0; k < H; ++k) { nin[H+k] = magg[(size_t)n*H+k]; magg[(size_t)n*H+k] = 0.0f; }

    #pragma unroll 1
    for (int j = 0; j < H; ++j) {
        float a = b1[j];
        #pragma unroll
        for (int k = 0; k < 2*H; ++k) a += nin[k] * W1[j*2*H+k];
        sbuf[j][t] = silu(a);
    }
    float h1[H];
    #pragma unroll
    for (int k = 0; k < H; ++k) h1[k] = sbuf[k][t];

    #pragma unroll 1
    for (int j = 0; j < H; ++j) {
        float a = b2[j];
        #pragma unroll
        for (int k = 0; k < H; ++k) a += h1[k] * W2[j*H+k];
        h[(size_t)n*H+j] = nin[j] + a;
    }
}

// ---- output: forces = x @ lin_W.T ------------------------------------------
__global__ __launch_bounds__(256) void out_kernel(
    const float* __restrict__ x, const float* __restrict__ lin,
    float* __restrict__ out, int N)
{
    int n = blockIdx.x * blockDim.x + threadIdx.x;
    if (n >= N) return;
    float xr[DOUT];
    const float4* xp = (const float4*)(x + (size_t)n * DOUT);
    #pragma unroll
    for (int q = 0; q < DOUT/4; ++q) {
        float4 v = xp[q];
        xr[4*q+0]=v.x; xr[4*q+1]=v.y; xr[4*q+2]=v.z; xr[4*q+3]=v.w;
    }
    #pragma unroll
    for (int i = 0; i < 3; ++i) {
        float a = 0.0f;
        #pragma unroll
        for (int k = 0; k < DOUT; ++k) a += xr[k] * lin[i*DOUT+k];
        out[(size_t)n*3+i] = a;
    }
}

extern "C" void kernel_launch(void* const* d_in, const int* in_sizes, int n_in,
                              void* d_out, int out_size, void* d_ws, size_t ws_size,
                              hipStream_t stream) {
    const float* node_attrs = (const float*)d_in[0];
    const float* positions  = (const float*)d_in[1];
    const int*   edge_index = (const int*)d_in[2];
    const float* proj_W   = (const float*)d_in[3];
    const float* emb_in_W = (const float*)d_in[4];
    const float* emb_in_b = (const float*)d_in[5];
    const float* edge_W1  = (const float*)d_in[6];
    const float* edge_b1  = (const float*)d_in[7];
    const float* edge_W2  = (const float*)d_in[8];
    const float* edge_b2  = (const float*)d_in[9];
    const float* node_W1  = (const float*)d_in[10];
    const float* node_b1  = (const float*)d_in[11];
    const float* node_W2  = (const float*)d_in[12];
    const float* node_b2  = (const float*)d_in[13];
    const float* coord_W1 = (const float*)d_in[14];
    const float* coord_b1 = (const float*)d_in[15];
    const float* coord_W2 = (const float*)d_in[16];
    // d_in[17], d_in[18]: emb_out (unused / DCE'd in reference)
    const float* lin_W    = (const float*)d_in[19];

    const int N = in_sizes[0] / 3;
    const int E = in_sizes[2] / 2;
    const int* row = edge_index;
    const int* col = edge_index + E;

    float* x    = (float*)d_ws;
    float* h    = x + (size_t)16 * N;
    float* xsum = h + (size_t)32 * N;
    float* cnt  = xsum + (size_t)16 * N;
    float* magg = cnt + (size_t)N;

    int nBlocks = (N + 255) / 256;
    int eBlocks = (E + 255) / 256;

    init_nodes<<<nBlocks, 256, 0, stream>>>(node_attrs, positions,
                                            proj_W, emb_in_W, emb_in_b,
                                            x, h, xsum, cnt, magg, N);

    for (int l = 0; l < 2; ++l) {
        edge_kernel<<<eBlocks, 256, 0, stream>>>(
            row, col, positions, x, h,
            edge_W1 + l * (H * EIN_DIM), edge_b1 + l * H,
            edge_W2 + l * (H * H),       edge_b2 + l * H,
            coord_W1 + l * (H * H),      coord_b1 + l * H,
            coord_W2 + l * H,
            xsum, cnt, magg, E);
        node_kernel<<<nBlocks, 256, 0, stream>>>(
            node_W1 + l * (H * 2 * H), node_b1 + l * H,
            node_W2 + l * (H * H),     node_b2 + l * H,
            x, h, xsum, cnt, magg, N);
    }

    out_kernel<<<nBlocks, 256, 0, stream>>>(x, lin_W, (float*)d_out, N);
}

// Round 4
// 2884.294 us; speedup vs baseline: 2.8130x; 2.8130x over previous
//
#include <hip/hip_runtime.h>

#define H 32
#define DOUT 16
#define BN 64   // layer_kernel block = 1 wave; 782 blocks spread ~3/CU

__device__ __forceinline__ float silu(float v) {
    return v * __builtin_amdgcn_rcpf(1.0f + __expf(-v));
}

// ---- CSR build: deg histogram -> exclusive scan -> scatter edge ids --------
__global__ __launch_bounds__(256) void zero_deg(int* __restrict__ deg, int N) {
    int i = blockIdx.x * blockDim.x + threadIdx.x;
    if (i < N) deg[i] = 0;
}

__global__ __launch_bounds__(256) void hist_kernel(const int* __restrict__ row,
                                                   int* __restrict__ deg, int E) {
    int e = blockIdx.x * blockDim.x + threadIdx.x;
    if (e < E) atomicAdd(&deg[row[e]], 1);
}

// single block of 1024: chunked serial sums + Hillis-Steele scan over partials
__global__ __launch_bounds__(1024) void scan_kernel(const int* __restrict__ deg,
                                                    int* __restrict__ start,
                                                    int* __restrict__ cursor, int N) {
    __shared__ int part[1024];
    int t = threadIdx.x;
    int ch = (N + 1023) >> 10;
    int lo = t * ch, hi = min(lo + ch, N);
    int s = 0;
    for (int i = lo; i < hi; ++i) s += deg[i];
    part[t] = s;
    __syncthreads();
    for (int off = 1; off < 1024; off <<= 1) {
        int v = (t >= off) ? part[t - off] : 0;
        __syncthreads();
        part[t] += v;
        __syncthreads();
    }
    int run = part[t] - s;  // exclusive prefix
    for (int i = lo; i < hi; ++i) {
        start[i] = run; cursor[i] = run;
        run += deg[i];
    }
}

__global__ __launch_bounds__(256) void scatter_kernel(const int* __restrict__ row,
                                                      int* __restrict__ cursor,
                                                      int* __restrict__ eidx, int E) {
    int e = blockIdx.x * blockDim.x + threadIdx.x;
    if (e < E) {
        int p = atomicAdd(&cursor[row[e]], 1);
        eidx[p] = e;
    }
}

// ---- init: x = pos@projW.T, h = attrs@embW.T + b ---------------------------
__global__ __launch_bounds__(256) void init_nodes(
    const float* __restrict__ node_attrs, const float* __restrict__ positions,
    const float* __restrict__ projW, const float* __restrict__ embW,
    const float* __restrict__ embB,
    float* __restrict__ x, float* __restrict__ h, int N)
{
    int n = blockIdx.x * blockDim.x + threadIdx.x;
    if (n >= N) return;
    float p0 = positions[3*n+0], p1 = positions[3*n+1], p2 = positions[3*n+2];
    #pragma unroll
    for (int i = 0; i < DOUT; ++i)
        x[(size_t)n*DOUT+i] = projW[i*3+0]*p0 + projW[i*3+1]*p1 + projW[i*3+2]*p2;
    float a0 = node_attrs[3*n+0], a1 = node_attrs[3*n+1], a2 = node_attrs[3*n+2];
    #pragma unroll
    for (int j = 0; j < H; ++j)
        h[(size_t)n*H+j] = embB[j] + embW[j*3+0]*a0 + embW[j*3+1]*a1 + embW[j*3+2]*a2;
}

// ---- fused layer: per node, gather out-edges, edge MLP + aggregation + node MLP
// No atomics, no inter-thread comm (mbuf column per thread, no barriers).
__global__ __launch_bounds__(BN) void layer_kernel(
    const int* __restrict__ start, const int* __restrict__ deg,
    const int* __restrict__ eidx, const int* __restrict__ col,
    const float* __restrict__ positions,
    const float* __restrict__ x_in, const float* __restrict__ h_in,
    const float* __restrict__ eW1, const float* __restrict__ eb1,
    const float* __restrict__ eW2, const float* __restrict__ eb2,
    const float* __restrict__ cW1, const float* __restrict__ cb1,
    const float* __restrict__ cW2,
    const float* __restrict__ nW1, const float* __restrict__ nb1,
    const float* __restrict__ nW2, const float* __restrict__ nb2,
    float* __restrict__ x_out, float* __restrict__ h_out, int N)
{
    __shared__ float mbuf[H][BN];  // [j][tid]: lanes stride-1 -> conflict-free
    int n = blockIdx.x * BN + threadIdx.x;
    if (n >= N) return;
    int t = threadIdx.x;

    int s0 = start[n], dg = deg[n];

    float xr[DOUT];
    {
        const float4* xp = (const float4*)(x_in + (size_t)n * DOUT);
        #pragma unroll
        for (int q = 0; q < DOUT/4; ++q) {
            float4 v = xp[q];
            xr[4*q+0]=v.x; xr[4*q+1]=v.y; xr[4*q+2]=v.z; xr[4*q+3]=v.w;
        }
    }
    float hr[H];
    {
        const float4* hp = (const float4*)(h_in + (size_t)n * H);
        #pragma unroll
        for (int q = 0; q < H/4; ++q) {
            float4 v = hp[q];
            hr[4*q+0]=v.x; hr[4*q+1]=v.y; hr[4*q+2]=v.z; hr[4*q+3]=v.w;
        }
    }
    float pr0 = positions[3*n+0], pr1 = positions[3*n+1], pr2 = positions[3*n+2];

    float xs[DOUT];
    #pragma unroll
    for (int i = 0; i < DOUT; ++i) xs[i] = 0.0f;
    float ma[H];
    #pragma unroll
    for (int k = 0; k < H; ++k) ma[k] = 0.0f;

    for (int i = 0; i < dg; ++i) {
        int e = eidx[s0 + i];
        int c = col[e];

        float cd[DOUT];
        {
            const float4* xc = (const float4*)(x_in + (size_t)c * DOUT);
            #pragma unroll
            for (int q = 0; q < DOUT/4; ++q) {
                float4 v = xc[q];
                cd[4*q+0] = xr[4*q+0]-v.x; cd[4*q+1] = xr[4*q+1]-v.y;
                cd[4*q+2] = xr[4*q+2]-v.z; cd[4*q+3] = xr[4*q+3]-v.w;
            }
        }
        float radial = 0.0f;
        #pragma unroll
        for (int i2 = 0; i2 < DOUT; ++i2) radial += cd[i2] * cd[i2];

        float hc[H];
        {
            const float4* hp = (const float4*)(h_in + (size_t)c * H);
            #pragma unroll
            for (int q = 0; q < H/4; ++q) {
                float4 v = hp[q];
                hc[4*q+0]=v.x; hc[4*q+1]=v.y; hc[4*q+2]=v.z; hc[4*q+3]=v.w;
            }
        }
        float ea0 = pr0 - positions[3*c+0];
        float ea1 = pr1 - positions[3*c+1];
        float ea2 = pr2 - positions[3*c+2];

        // edge MLP 1: 68 -> 32 silu (weights uniform -> s_load)
        #pragma unroll 1
        for (int j = 0; j < H; ++j) {
            const float* wj = eW1 + j * 68;
            float a = eb1[j];
            #pragma unroll
            for (int k = 0; k < H; ++k) a += hr[k] * wj[k];
            #pragma unroll
            for (int k = 0; k < H; ++k) a += hc[k] * wj[32+k];
            a += radial * wj[64] + ea0 * wj[65] + ea1 * wj[66] + ea2 * wj[67];
            mbuf[j][t] = silu(a);
        }
        float m1[H];
        #pragma unroll
        for (int k = 0; k < H; ++k) m1[k] = mbuf[k][t];

        // edge MLP 2: 32 -> 32 silu
        #pragma unroll 1
        for (int j = 0; j < H; ++j) {
            const float* wj = eW2 + j * H;
            float a = eb2[j];
            #pragma unroll
            for (int k = 0; k < H; ++k) a += m1[k] * wj[k];
            mbuf[j][t] = silu(a);
        }
        float m2[H];
        #pragma unroll
        for (int k = 0; k < H; ++k) { m2[k] = mbuf[k][t]; ma[k] += m2[k]; }

        // coord MLP: 32 -> 32 silu -> 1
        float cm = 0.0f;
        #pragma unroll 1
        for (int j = 0; j < H; ++j) {
            const float* wj = cW1 + j * H;
            float a = cb1[j];
            #pragma unroll
            for (int k = 0; k < H; ++k) a += m2[k] * wj[k];
            cm += silu(a) * cW2[j];
        }

        #pragma unroll
        for (int i2 = 0; i2 < DOUT; ++i2) xs[i2] += cd[i2] * cm;
    }

    // coordinate update: x += sums / max(cnt,1)
    float inv = __builtin_amdgcn_rcpf(fmaxf((float)dg, 1.0f));
    {
        float4* xo = (float4*)(x_out + (size_t)n * DOUT);
        #pragma unroll
        for (int q = 0; q < DOUT/4; ++q) {
            float4 v;
            v.x = xr[4*q+0] + xs[4*q+0]*inv; v.y = xr[4*q+1] + xs[4*q+1]*inv;
            v.z = xr[4*q+2] + xs[4*q+2]*inv; v.w = xr[4*q+3] + xs[4*q+3]*inv;
            xo[q] = v;
        }
    }

    // node MLP: [h, m_agg] (64) -> 32 silu -> 32, residual
    #pragma unroll 1
    for (int j = 0; j < H; ++j) {
        const float* wj = nW1 + j * 2 * H;
        float a = nb1[j];
        #pragma unroll
        for (int k = 0; k < H; ++k) a += hr[k] * wj[k];
        #pragma unroll
        for (int k = 0; k < H; ++k) a += ma[k] * wj[32+k];
        mbuf[j][t] = silu(a);
    }
    float u1[H];
    #pragma unroll
    for (int k = 0; k < H; ++k) u1[k] = mbuf[k][t];

    #pragma unroll 1
    for (int j = 0; j < H; ++j) {
        const float* wj = nW2 + j * H;
        float a = nb2[j];
        #pragma unroll
        for (int k = 0; k < H; ++k) a += u1[k] * wj[k];
        mbuf[j][t] = a;  // delta (residual added below with compile-time index)
    }
    {
        float4* ho = (float4*)(h_out + (size_t)n * H);
        #pragma unroll
        for (int q = 0; q < H/4; ++q) {
            float4 v;
            v.x = hr[4*q+0] + mbuf[4*q+0][t]; v.y = hr[4*q+1] + mbuf[4*q+1][t];
            v.z = hr[4*q+2] + mbuf[4*q+2][t]; v.w = hr[4*q+3] + mbuf[4*q+3][t];
            ho[q] = v;
        }
    }
}

// ---- output: forces = x @ lin_W.T ------------------------------------------
__global__ __launch_bounds__(256) void out_kernel(
    const float* __restrict__ x, const float* __restrict__ lin,
    float* __restrict__ out, int N)
{
    int n = blockIdx.x * blockDim.x + threadIdx.x;
    if (n >= N) return;
    float xr[DOUT];
    const float4* xp = (const float4*)(x + (size_t)n * DOUT);
    #pragma unroll
    for (int q = 0; q < DOUT/4; ++q) {
        float4 v = xp[q];
        xr[4*q+0]=v.x; xr[4*q+1]=v.y; xr[4*q+2]=v.z; xr[4*q+3]=v.w;
    }
    #pragma unroll
    for (int i = 0; i < 3; ++i) {
        float a = 0.0f;
        #pragma unroll
        for (int k = 0; k < DOUT; ++k) a += xr[k] * lin[i*DOUT+k];
        out[(size_t)n*3+i] = a;
    }
}

extern "C" void kernel_launch(void* const* d_in, const int* in_sizes, int n_in,
                              void* d_out, int out_size, void* d_ws, size_t ws_size,
                              hipStream_t stream) {
    const float* node_attrs = (const float*)d_in[0];
    const float* positions  = (const float*)d_in[1];
    const int*   edge_index = (const int*)d_in[2];
    const float* proj_W   = (const float*)d_in[3];
    const float* emb_in_W = (const float*)d_in[4];
    const float* emb_in_b = (const float*)d_in[5];
    const float* edge_W1  = (const float*)d_in[6];
    const float* edge_b1  = (const float*)d_in[7];
    const float* edge_W2  = (const float*)d_in[8];
    const float* edge_b2  = (const float*)d_in[9];
    const float* node_W1  = (const float*)d_in[10];
    const float* node_b1  = (const float*)d_in[11];
    const float* node_W2  = (const float*)d_in[12];
    const float* node_b2  = (const float*)d_in[13];
    const float* coord_W1 = (const float*)d_in[14];
    const float* coord_b1 = (const float*)d_in[15];
    const float* coord_W2 = (const float*)d_in[16];
    const float* lin_W    = (const float*)d_in[19];

    const int N = in_sizes[0] / 3;
    const int E = in_sizes[2] / 2;
    const int* row = edge_index;
    const int* col = edge_index + E;

    // ws layout: x0,h0,x1,h1 (fp32) | deg,start,cursor (int N) | eidx (int E) ~ 26 MB
    float* x0 = (float*)d_ws;
    float* h0 = x0 + (size_t)DOUT * N;
    float* x1 = h0 + (size_t)H * N;
    float* h1 = x1 + (size_t)DOUT * N;
    int* deg    = (int*)(h1 + (size_t)H * N);
    int* startv = deg + N;
    int* cursor = startv + N;
    int* eidx   = cursor + N;

    int nB256 = (N + 255) / 256;
    int eB256 = (E + 255) / 256;
    int nBofBN = (N + BN - 1) / BN;

    zero_deg<<<nB256, 256, 0, stream>>>(deg, N);
    hist_kernel<<<eB256, 256, 0, stream>>>(row, deg, E);
    scan_kernel<<<1, 1024, 0, stream>>>(deg, startv, cursor, N);
    scatter_kernel<<<eB256, 256, 0, stream>>>(row, cursor, eidx, E);

    init_nodes<<<nB256, 256, 0, stream>>>(node_attrs, positions,
                                          proj_W, emb_in_W, emb_in_b, x0, h0, N);

    const float* xi = x0; const float* hi = h0;
    float* xo = x1; float* ho = h1;
    for (int l = 0; l < 2; ++l) {
        layer_kernel<<<nBofBN, BN, 0, stream>>>(
            startv, deg, eidx, col, positions, xi, hi,
            edge_W1 + l * (H * 68), edge_b1 + l * H,
            edge_W2 + l * (H * H), edge_b2 + l * H,
            coord_W1 + l * (H * H), coord_b1 + l * H,
            coord_W2 + l * H,
            node_W1 + l * (H * 2 * H), node_b1 + l * H,
            node_W2 + l * (H * H), node_b2 + l * H,
            (float*)xo, (float*)ho, N);
        const float* tx = xi; xi = xo; xo = (float*)tx;
        const float* th = hi; hi = ho; ho = (float*)th;
    }

    out_kernel<<<nB256, 256, 0, stream>>>(xi, lin_W, (float*)d_out, N);
}

// Round 5
// 1528.187 us; speedup vs baseline: 5.3092x; 1.8874x over previous
//
#include <hip/hip_runtime.h>

#define H 32
#define DOUT 16
#define T 8     // threads per node in edge kernel
#define BLK 256

__device__ __forceinline__ float silu(float v) {
    return v * __builtin_amdgcn_rcpf(1.0f + __expf(-v));
}

// ---- CSR build: deg histogram -> exclusive scan -> scatter reordered col ---
__global__ __launch_bounds__(256) void zero_deg(int* __restrict__ deg, int N) {
    int i = blockIdx.x * blockDim.x + threadIdx.x;
    if (i < N) deg[i] = 0;
}

__global__ __launch_bounds__(256) void hist_kernel(const int* __restrict__ row,
                                                   int* __restrict__ deg, int E) {
    int e = blockIdx.x * blockDim.x + threadIdx.x;
    if (e < E) atomicAdd(&deg[row[e]], 1);
}

// single block of 1024: chunked serial sums + Hillis-Steele scan over partials
__global__ __launch_bounds__(1024) void scan_kernel(const int* __restrict__ deg,
                                                    int* __restrict__ start,
                                                    int* __restrict__ cursor, int N) {
    __shared__ int part[1024];
    int t = threadIdx.x;
    int ch = (N + 1023) >> 10;
    int lo = t * ch, hi = min(lo + ch, N);
    int s = 0;
    for (int i = lo; i < hi; ++i) s += deg[i];
    part[t] = s;
    __syncthreads();
    for (int off = 1; off < 1024; off <<= 1) {
        int v = (t >= off) ? part[t - off] : 0;
        __syncthreads();
        part[t] += v;
        __syncthreads();
    }
    int run = part[t] - s;  // exclusive prefix
    for (int i = lo; i < hi; ++i) {
        start[i] = run; cursor[i] = run;
        run += deg[i];
    }
}

// stores reordered col directly: ecol[slot] = col[e] (kills one indirection)
__global__ __launch_bounds__(256) void scatter_kernel(const int* __restrict__ row,
                                                      const int* __restrict__ col,
                                                      int* __restrict__ cursor,
                                                      int* __restrict__ ecol, int E) {
    int e = blockIdx.x * blockDim.x + threadIdx.x;
    if (e < E) {
        int p = atomicAdd(&cursor[row[e]], 1);
        ecol[p] = col[e];
    }
}

// ---- init: x = pos@projW.T, h = attrs@embW.T + b ---------------------------
__global__ __launch_bounds__(256) void init_nodes(
    const float* __restrict__ node_attrs, const float* __restrict__ positions,
    const float* __restrict__ projW, const float* __restrict__ embW,
    const float* __restrict__ embB,
    float* __restrict__ x, float* __restrict__ h, int N)
{
    int n = blockIdx.x * blockDim.x + threadIdx.x;
    if (n >= N) return;
    float p0 = positions[3*n+0], p1 = positions[3*n+1], p2 = positions[3*n+2];
    #pragma unroll
    for (int i = 0; i < DOUT; ++i)
        x[(size_t)n*DOUT+i] = projW[i*3+0]*p0 + projW[i*3+1]*p1 + projW[i*3+2]*p2;
    float a0 = node_attrs[3*n+0], a1 = node_attrs[3*n+1], a2 = node_attrs[3*n+2];
    #pragma unroll
    for (int j = 0; j < H; ++j)
        h[(size_t)n*H+j] = embB[j] + embW[j*3+0]*a0 + embW[j*3+1]*a1 + embW[j*3+2]*a2;
}

// ---- edge kernel: T threads per node, shuffle-reduced partials, no atomics -
__global__ __launch_bounds__(BLK) void edge_kernel(
    const int* __restrict__ start, const int* __restrict__ deg,
    const int* __restrict__ ecol,
    const float* __restrict__ positions,
    const float* __restrict__ x_in, const float* __restrict__ h_in,
    const float* __restrict__ eW1, const float* __restrict__ eb1,
    const float* __restrict__ eW2, const float* __restrict__ eb2,
    const float* __restrict__ cW1, const float* __restrict__ cb1,
    const float* __restrict__ cW2,
    float* __restrict__ xsum, float* __restrict__ magg, int N)
{
    __shared__ float mbuf[H][BLK];  // [j][tid]: lanes stride-1 -> conflict-free
    int gid = blockIdx.x * BLK + threadIdx.x;
    int n = gid >> 3, sub = gid & (T - 1);
    if (n >= N) return;
    int t = threadIdx.x;

    int s0 = start[n], dg = deg[n];

    float xr[DOUT];
    {
        const float4* xp = (const float4*)(x_in + (size_t)n * DOUT);
        #pragma unroll
        for (int q = 0; q < DOUT/4; ++q) {
            float4 v = xp[q];
            xr[4*q+0]=v.x; xr[4*q+1]=v.y; xr[4*q+2]=v.z; xr[4*q+3]=v.w;
        }
    }
    float hr[H];
    {
        const float4* hp = (const float4*)(h_in + (size_t)n * H);
        #pragma unroll
        for (int q = 0; q < H/4; ++q) {
            float4 v = hp[q];
            hr[4*q+0]=v.x; hr[4*q+1]=v.y; hr[4*q+2]=v.z; hr[4*q+3]=v.w;
        }
    }
    float pr0 = positions[3*n+0], pr1 = positions[3*n+1], pr2 = positions[3*n+2];

    float xs[DOUT];
    #pragma unroll
    for (int i = 0; i < DOUT; ++i) xs[i] = 0.0f;
    float ma[H];
    #pragma unroll
    for (int k = 0; k < H; ++k) ma[k] = 0.0f;

    for (int i = sub; i < dg; i += T) {
        int c = ecol[s0 + i];

        float cd[DOUT];
        {
            const float4* xc = (const float4*)(x_in + (size_t)c * DOUT);
            #pragma unroll
            for (int q = 0; q < DOUT/4; ++q) {
                float4 v = xc[q];
                cd[4*q+0] = xr[4*q+0]-v.x; cd[4*q+1] = xr[4*q+1]-v.y;
                cd[4*q+2] = xr[4*q+2]-v.z; cd[4*q+3] = xr[4*q+3]-v.w;
            }
        }
        float radial = 0.0f;
        #pragma unroll
        for (int i2 = 0; i2 < DOUT; ++i2) radial += cd[i2] * cd[i2];

        float hc[H];
        {
            const float4* hp = (const float4*)(h_in + (size_t)c * H);
            #pragma unroll
            for (int q = 0; q < H/4; ++q) {
                float4 v = hp[q];
                hc[4*q+0]=v.x; hc[4*q+1]=v.y; hc[4*q+2]=v.z; hc[4*q+3]=v.w;
            }
        }
        float ea0 = pr0 - positions[3*c+0];
        float ea1 = pr1 - positions[3*c+1];
        float ea2 = pr2 - positions[3*c+2];

        // edge MLP 1: 68 -> 32 silu (weights uniform -> s_load)
        #pragma unroll 1
        for (int j = 0; j < H; ++j) {
            const float* wj = eW1 + j * 68;
            float a = eb1[j];
            #pragma unroll
            for (int k = 0; k < H; ++k) a += hr[k] * wj[k];
            #pragma unroll
            for (int k = 0; k < H; ++k) a += hc[k] * wj[32+k];
            a += radial * wj[64] + ea0 * wj[65] + ea1 * wj[66] + ea2 * wj[67];
            mbuf[j][t] = silu(a);
        }
        float m1[H];
        #pragma unroll
        for (int k = 0; k < H; ++k) m1[k] = mbuf[k][t];

        // edge MLP 2: 32 -> 32 silu
        #pragma unroll 1
        for (int j = 0; j < H; ++j) {
            const float* wj = eW2 + j * H;
            float a = eb2[j];
            #pragma unroll
            for (int k = 0; k < H; ++k) a += m1[k] * wj[k];
            mbuf[j][t] = silu(a);
        }
        float m2[H];
        #pragma unroll
        for (int k = 0; k < H; ++k) { m2[k] = mbuf[k][t]; ma[k] += m2[k]; }

        // coord MLP: 32 -> 32 silu -> 1
        float cm = 0.0f;
        #pragma unroll 1
        for (int j = 0; j < H; ++j) {
            const float* wj = cW1 + j * H;
            float a = cb1[j];
            #pragma unroll
            for (int k = 0; k < H; ++k) a += m2[k] * wj[k];
            cm += silu(a) * cW2[j];
        }

        #pragma unroll
        for (int i2 = 0; i2 < DOUT; ++i2) xs[i2] += cd[i2] * cm;
    }

    // reduce partials across the T adjacent lanes of this node (same wave)
    #pragma unroll
    for (int m = 1; m < T; m <<= 1) {
        #pragma unroll
        for (int k = 0; k < H; ++k) ma[k] += __shfl_xor(ma[k], m, 64);
        #pragma unroll
        for (int i = 0; i < DOUT; ++i) xs[i] += __shfl_xor(xs[i], m, 64);
    }

    if (sub == 0) {
        float4* mo = (float4*)(magg + (size_t)n * H);
        #pragma unroll
        for (int q = 0; q < H/4; ++q) {
            float4 v; v.x=ma[4*q+0]; v.y=ma[4*q+1]; v.z=ma[4*q+2]; v.w=ma[4*q+3];
            mo[q] = v;
        }
        float4* xo = (float4*)(xsum + (size_t)n * DOUT);
        #pragma unroll
        for (int q = 0; q < DOUT/4; ++q) {
            float4 v; v.x=xs[4*q+0]; v.y=xs[4*q+1]; v.z=xs[4*q+2]; v.w=xs[4*q+3];
            xo[q] = v;
        }
    }
}

// ---- node update: x += xsum/max(deg,1); h += MLP([h, m_agg]) ---------------
__global__ __launch_bounds__(256) void node_kernel(
    const int* __restrict__ deg,
    const float* __restrict__ x_in, const float* __restrict__ h_in,
    const float* __restrict__ xsum, const float* __restrict__ magg,
    const float* __restrict__ W1, const float* __restrict__ b1,
    const float* __restrict__ W2, const float* __restrict__ b2,
    float* __restrict__ x_out, float* __restrict__ h_out, int N)
{
    __shared__ float sbuf[H][256];
    int n = blockIdx.x * blockDim.x + threadIdx.x;
    if (n >= N) return;
    int t = threadIdx.x;

    float inv = __builtin_amdgcn_rcpf(fmaxf((float)deg[n], 1.0f));
    {
        const float4* xi = (const float4*)(x_in + (size_t)n * DOUT);
        const float4* xa = (const float4*)(xsum + (size_t)n * DOUT);
        float4* xo = (float4*)(x_out + (size_t)n * DOUT);
        #pragma unroll
        for (int q = 0; q < DOUT/4; ++q) {
            float4 a = xi[q], b = xa[q];
            float4 v; v.x=a.x+b.x*inv; v.y=a.y+b.y*inv; v.z=a.z+b.z*inv; v.w=a.w+b.w*inv;
            xo[q] = v;
        }
    }

    float hr[H], ma[H];
    {
        const float4* hp = (const float4*)(h_in + (size_t)n * H);
        const float4* mp = (const float4*)(magg + (size_t)n * H);
        #pragma unroll
        for (int q = 0; q < H/4; ++q) {
            float4 v = hp[q];
            hr[4*q+0]=v.x; hr[4*q+1]=v.y; hr[4*q+2]=v.z; hr[4*q+3]=v.w;
            float4 u = mp[q];
            ma[4*q+0]=u.x; ma[4*q+1]=u.y; ma[4*q+2]=u.z; ma[4*q+3]=u.w;
        }
    }

    #pragma unroll 1
    for (int j = 0; j < H; ++j) {
        const float* wj = W1 + j * 2 * H;
        float a = b1[j];
        #pragma unroll
        for (int k = 0; k < H; ++k) a += hr[k] * wj[k];
        #pragma unroll
        for (int k = 0; k < H; ++k) a += ma[k] * wj[32+k];
        sbuf[j][t] = silu(a);
    }
    float u1[H];
    #pragma unroll
    for (int k = 0; k < H; ++k) u1[k] = sbuf[k][t];

    #pragma unroll 1
    for (int j = 0; j < H; ++j) {
        const float* wj = W2 + j * H;
        float a = b2[j];
        #pragma unroll
        for (int k = 0; k < H; ++k) a += u1[k] * wj[k];
        sbuf[j][t] = a;
    }
    {
        float4* ho = (float4*)(h_out + (size_t)n * H);
        #pragma unroll
        for (int q = 0; q < H/4; ++q) {
            float4 v;
            v.x = hr[4*q+0] + sbuf[4*q+0][t]; v.y = hr[4*q+1] + sbuf[4*q+1][t];
            v.z = hr[4*q+2] + sbuf[4*q+2][t]; v.w = hr[4*q+3] + sbuf[4*q+3][t];
            ho[q] = v;
        }
    }
}

// ---- output: forces = x @ lin_W.T ------------------------------------------
__global__ __launch_bounds__(256) void out_kernel(
    const float* __restrict__ x, const float* __restrict__ lin,
    float* __restrict__ out, int N)
{
    int n = blockIdx.x * blockDim.x + threadIdx.x;
    if (n >= N) return;
    float xr[DOUT];
    const float4* xp = (const float4*)(x + (size_t)n * DOUT);
    #pragma unroll
    for (int q = 0; q < DOUT/4; ++q) {
        float4 v = xp[q];
        xr[4*q+0]=v.x; xr[4*q+1]=v.y; xr[4*q+2]=v.z; xr[4*q+3]=v.w;
    }
    #pragma unroll
    for (int i = 0; i < 3; ++i) {
        float a = 0.0f;
        #pragma unroll
        for (int k = 0; k < DOUT; ++k) a += xr[k] * lin[i*DOUT+k];
        out[(size_t)n*3+i] = a;
    }
}

extern "C" void kernel_launch(void* const* d_in, const int* in_sizes, int n_in,
                              void* d_out, int out_size, void* d_ws, size_t ws_size,
                              hipStream_t stream) {
    const float* node_attrs = (const float*)d_in[0];
    const float* positions  = (const float*)d_in[1];
    const int*   edge_index = (const int*)d_in[2];
    const float* proj_W   = (const float*)d_in[3];
    const float* emb_in_W = (const float*)d_in[4];
    const float* emb_in_b = (const float*)d_in[5];
    const float* edge_W1  = (const float*)d_in[6];
    const float* edge_b1  = (const float*)d_in[7];
    const float* edge_W2  = (const float*)d_in[8];
    const float* edge_b2  = (const float*)d_in[9];
    const float* node_W1  = (const float*)d_in[10];
    const float* node_b1  = (const float*)d_in[11];
    const float* node_W2  = (const float*)d_in[12];
    const float* node_b2  = (const float*)d_in[13];
    const float* coord_W1 = (const float*)d_in[14];
    const float* coord_b1 = (const float*)d_in[15];
    const float* coord_W2 = (const float*)d_in[16];
    const float* lin_W    = (const float*)d_in[19];

    const int N = in_sizes[0] / 3;
    const int E = in_sizes[2] / 2;
    const int* row = edge_index;
    const int* col = edge_index + E;

    // ws: x0,h0,x1,h1 | xsum(16N), magg(32N) | deg,start,cursor(N), ecol(E)
    float* x0 = (float*)d_ws;
    float* h0 = x0 + (size_t)DOUT * N;
    float* x1 = h0 + (size_t)H * N;
    float* h1 = x1 + (size_t)DOUT * N;
    float* xsum = h1 + (size_t)H * N;
    float* magg = xsum + (size_t)DOUT * N;
    int* deg    = (int*)(magg + (size_t)H * N);
    int* startv = deg + N;
    int* cursor = startv + N;
    int* ecol   = cursor + N;

    int nB256 = (N + 255) / 256;
    int eB256 = (E + 255) / 256;
    int egBlocks = ((size_t)N * T + BLK - 1) / BLK;

    zero_deg<<<nB256, 256, 0, stream>>>(deg, N);
    hist_kernel<<<eB256, 256, 0, stream>>>(row, deg, E);
    scan_kernel<<<1, 1024, 0, stream>>>(deg, startv, cursor, N);
    scatter_kernel<<<eB256, 256, 0, stream>>>(row, col, cursor, ecol, E);

    init_nodes<<<nB256, 256, 0, stream>>>(node_attrs, positions,
                                          proj_W, emb_in_W, emb_in_b, x0, h0, N);

    const float* xi = x0; const float* hi = h0;
    float* xo = x1; float* ho = h1;
    for (int l = 0; l < 2; ++l) {
        edge_kernel<<<egBlocks, BLK, 0, stream>>>(
            startv, deg, ecol, positions, xi, hi,
            edge_W1 + l * (H * 68), edge_b1 + l * H,
            edge_W2 + l * (H * H), edge_b2 + l * H,
            coord_W1 + l * (H * H), coord_b1 + l * H,
            coord_W2 + l * H,
            xsum, magg, N);
        node_kernel<<<nB256, 256, 0, stream>>>(
            deg, xi, hi, xsum, magg,
            node_W1 + l * (H * 2 * H), node_b1 + l * H,
            node_W2 + l * (H * H),     node_b2 + l * H,
            xo, ho, N);
        const float* tx = xi; xi = xo; xo = (float*)tx;
        const float* th = hi; hi = ho; ho = (float*)th;
    }

    out_kernel<<<nB256, 256, 0, stream>>>(xi, lin_W, (float*)d_out, N);
}

// Round 6
// 1455.388 us; speedup vs baseline: 5.5748x; 1.0500x over previous
//
#include <hip/hip_runtime.h>

#define H 32
#define DOUT 16
#define T 8     // threads per node in edge kernel
#define BLK 256

__device__ __forceinline__ float silu(float v) {
    return v * __builtin_amdgcn_rcpf(1.0f + __expf(-v));
}

// ---- CSR build: deg histogram -> exclusive scan -> scatter reordered col ---
__global__ __launch_bounds__(256) void zero_deg(int* __restrict__ deg, int N) {
    int i = blockIdx.x * blockDim.x + threadIdx.x;
    if (i < N) deg[i] = 0;
}

__global__ __launch_bounds__(256) void hist_kernel(const int* __restrict__ row,
                                                   int* __restrict__ deg, int E) {
    int e = blockIdx.x * blockDim.x + threadIdx.x;
    if (e < E) atomicAdd(&deg[row[e]], 1);
}

// single block of 1024: chunked serial sums + Hillis-Steele scan over partials
__global__ __launch_bounds__(1024) void scan_kernel(const int* __restrict__ deg,
                                                    int* __restrict__ start,
                                                    int* __restrict__ cursor, int N) {
    __shared__ int part[1024];
    int t = threadIdx.x;
    int ch = (N + 1023) >> 10;
    int lo = t * ch, hi = min(lo + ch, N);
    int s = 0;
    for (int i = lo; i < hi; ++i) s += deg[i];
    part[t] = s;
    __syncthreads();
    for (int off = 1; off < 1024; off <<= 1) {
        int v = (t >= off) ? part[t - off] : 0;
        __syncthreads();
        part[t] += v;
        __syncthreads();
    }
    int run = part[t] - s;  // exclusive prefix
    for (int i = lo; i < hi; ++i) {
        start[i] = run; cursor[i] = run;
        run += deg[i];
    }
}

// stores reordered col directly: ecol[slot] = col[e]
__global__ __launch_bounds__(256) void scatter_kernel(const int* __restrict__ row,
                                                      const int* __restrict__ col,
                                                      int* __restrict__ cursor,
                                                      int* __restrict__ ecol, int E) {
    int e = blockIdx.x * blockDim.x + threadIdx.x;
    if (e < E) {
        int p = atomicAdd(&cursor[row[e]], 1);
        ecol[p] = col[e];
    }
}

// ---- transpose edge_W2 (both layers): W2T[l][j][i] = W2[l][i][j] -----------
__global__ __launch_bounds__(256) void transpose_w2(const float* __restrict__ W2,
                                                    float* __restrict__ W2T) {
    int i = blockIdx.x * blockDim.x + threadIdx.x;
    if (i >= 2 * H * H) return;
    int l = i >> 10, r = (i >> 5) & 31, c = i & 31;   // W2[l][r][c]
    W2T[l * H * H + c * H + r] = W2[i];
}

// ---- init: x = pos@projW.T, h = attrs@embW.T + b ---------------------------
__global__ __launch_bounds__(256) void init_nodes(
    const float* __restrict__ node_attrs, const float* __restrict__ positions,
    const float* __restrict__ projW, const float* __restrict__ embW,
    const float* __restrict__ embB,
    float* __restrict__ x, float* __restrict__ h, int N)
{
    int n = blockIdx.x * blockDim.x + threadIdx.x;
    if (n >= N) return;
    float p0 = positions[3*n+0], p1 = positions[3*n+1], p2 = positions[3*n+2];
    #pragma unroll
    for (int i = 0; i < DOUT; ++i)
        x[(size_t)n*DOUT+i] = projW[i*3+0]*p0 + projW[i*3+1]*p1 + projW[i*3+2]*p2;
    float a0 = node_attrs[3*n+0], a1 = node_attrs[3*n+1], a2 = node_attrs[3*n+2];
    #pragma unroll
    for (int j = 0; j < H; ++j)
        h[(size_t)n*H+j] = embB[j] + embW[j*3+0]*a0 + embW[j*3+1]*a1 + embW[j*3+2]*a2;
}

// ---- edge kernel: T threads/node, all-register dataflow (no LDS), ----------
// MLP2 folded into MLP1 j-loop as rank-1 update with transposed W2.
__global__ __launch_bounds__(BLK) void edge_kernel(
    const int* __restrict__ start, const int* __restrict__ deg,
    const int* __restrict__ ecol,
    const float* __restrict__ positions,
    const float* __restrict__ x_in, const float* __restrict__ h_in,
    const float* __restrict__ eW1, const float* __restrict__ eb1,
    const float* __restrict__ W2T, const float* __restrict__ eb2,
    const float* __restrict__ cW1, const float* __restrict__ cb1,
    const float* __restrict__ cW2,
    float* __restrict__ xsum, float* __restrict__ magg, int N)
{
    int gid = blockIdx.x * BLK + threadIdx.x;
    int n = gid >> 3, sub = gid & (T - 1);
    if (n >= N) return;

    int s0 = start[n], dg = deg[n];

    float xr[DOUT];
    {
        const float4* xp = (const float4*)(x_in + (size_t)n * DOUT);
        #pragma unroll
        for (int q = 0; q < DOUT/4; ++q) {
            float4 v = xp[q];
            xr[4*q+0]=v.x; xr[4*q+1]=v.y; xr[4*q+2]=v.z; xr[4*q+3]=v.w;
        }
    }
    float hr[H];
    {
        const float4* hp = (const float4*)(h_in + (size_t)n * H);
        #pragma unroll
        for (int q = 0; q < H/4; ++q) {
            float4 v = hp[q];
            hr[4*q+0]=v.x; hr[4*q+1]=v.y; hr[4*q+2]=v.z; hr[4*q+3]=v.w;
        }
    }
    float pr0 = positions[3*n+0], pr1 = positions[3*n+1], pr2 = positions[3*n+2];

    float xs[DOUT];
    #pragma unroll
    for (int i = 0; i < DOUT; ++i) xs[i] = 0.0f;
    float ma[H];
    #pragma unroll
    for (int k = 0; k < H; ++k) ma[k] = 0.0f;

    for (int i = sub; i < dg; i += T) {
        int c = ecol[s0 + i];

        float cd[DOUT];
        {
            const float4* xc = (const float4*)(x_in + (size_t)c * DOUT);
            #pragma unroll
            for (int q = 0; q < DOUT/4; ++q) {
                float4 v = xc[q];
                cd[4*q+0] = xr[4*q+0]-v.x; cd[4*q+1] = xr[4*q+1]-v.y;
                cd[4*q+2] = xr[4*q+2]-v.z; cd[4*q+3] = xr[4*q+3]-v.w;
            }
        }
        float radial = 0.0f;
        #pragma unroll
        for (int i2 = 0; i2 < DOUT; ++i2) radial += cd[i2] * cd[i2];

        float hc[H];
        {
            const float4* hp = (const float4*)(h_in + (size_t)c * H);
            #pragma unroll
            for (int q = 0; q < H/4; ++q) {
                float4 v = hp[q];
                hc[4*q+0]=v.x; hc[4*q+1]=v.y; hc[4*q+2]=v.z; hc[4*q+3]=v.w;
            }
        }
        float ea0 = pr0 - positions[3*c+0];
        float ea1 = pr1 - positions[3*c+1];
        float ea2 = pr2 - positions[3*c+2];

        // MLP2 accumulators start at bias; MLP1 neuron j does rank-1 update
        float acc[H];
        #pragma unroll
        for (int k = 0; k < H; ++k) acc[k] = eb2[k];

        #pragma unroll 1
        for (int j = 0; j < H; ++j) {
            const float* wj = eW1 + j * 68;
            float a = eb1[j];
            #pragma unroll
            for (int k = 0; k < H; ++k) a += hr[k] * wj[k];
            #pragma unroll
            for (int k = 0; k < H; ++k) a += hc[k] * wj[32+k];
            a += radial * wj[64] + ea0 * wj[65] + ea1 * wj[66] + ea2 * wj[67];
            float m1j = silu(a);
            const float* w2j = W2T + j * H;   // column j of W2
            #pragma unroll
            for (int k = 0; k < H; ++k) acc[k] += m1j * w2j[k];
        }

        // m2 = silu(acc); aggregate
        #pragma unroll
        for (int k = 0; k < H; ++k) {
            float v = silu(acc[k]);
            acc[k] = v;
            ma[k] += v;
        }

        // coord MLP: 32 -> 32 silu -> 1
        float cm = 0.0f;
        #pragma unroll 1
        for (int j = 0; j < H; ++j) {
            const float* wj = cW1 + j * H;
            float a = cb1[j];
            #pragma unroll
            for (int k = 0; k < H; ++k) a += acc[k] * wj[k];
            cm += silu(a) * cW2[j];
        }

        #pragma unroll
        for (int i2 = 0; i2 < DOUT; ++i2) xs[i2] += cd[i2] * cm;
    }

    // reduce partials across the T adjacent lanes of this node (same wave)
    #pragma unroll
    for (int m = 1; m < T; m <<= 1) {
        #pragma unroll
        for (int k = 0; k < H; ++k) ma[k] += __shfl_xor(ma[k], m, 64);
        #pragma unroll
        for (int i = 0; i < DOUT; ++i) xs[i] += __shfl_xor(xs[i], m, 64);
    }

    if (sub == 0) {
        float4* mo = (float4*)(magg + (size_t)n * H);
        #pragma unroll
        for (int q = 0; q < H/4; ++q) {
            float4 v; v.x=ma[4*q+0]; v.y=ma[4*q+1]; v.z=ma[4*q+2]; v.w=ma[4*q+3];
            mo[q] = v;
        }
        float4* xo = (float4*)(xsum + (size_t)n * DOUT);
        #pragma unroll
        for (int q = 0; q < DOUT/4; ++q) {
            float4 v; v.x=xs[4*q+0]; v.y=xs[4*q+1]; v.z=xs[4*q+2]; v.w=xs[4*q+3];
            xo[q] = v;
        }
    }
}

// ---- node update: x += xsum/max(deg,1); h += MLP([h, m_agg]) ---------------
__global__ __launch_bounds__(256) void node_kernel(
    const int* __restrict__ deg,
    const float* __restrict__ x_in, const float* __restrict__ h_in,
    const float* __restrict__ xsum, const float* __restrict__ magg,
    const float* __restrict__ W1, const float* __restrict__ b1,
    const float* __restrict__ W2T, const float* __restrict__ b2,
    float* __restrict__ x_out, float* __restrict__ h_out, int N)
{
    int n = blockIdx.x * blockDim.x + threadIdx.x;
    if (n >= N) return;

    float inv = __builtin_amdgcn_rcpf(fmaxf((float)deg[n], 1.0f));
    {
        const float4* xi = (const float4*)(x_in + (size_t)n * DOUT);
        const float4* xa = (const float4*)(xsum + (size_t)n * DOUT);
        float4* xo = (float4*)(x_out + (size_t)n * DOUT);
        #pragma unroll
        for (int q = 0; q < DOUT/4; ++q) {
            float4 a = xi[q], b = xa[q];
            float4 v; v.x=a.x+b.x*inv; v.y=a.y+b.y*inv; v.z=a.z+b.z*inv; v.w=a.w+b.w*inv;
            xo[q] = v;
        }
    }

    float hr[H], ma[H];
    {
        const float4* hp = (const float4*)(h_in + (size_t)n * H);
        const float4* mp = (const float4*)(magg + (size_t)n * H);
        #pragma unroll
        for (int q = 0; q < H/4; ++q) {
            float4 v = hp[q];
            hr[4*q+0]=v.x; hr[4*q+1]=v.y; hr[4*q+2]=v.z; hr[4*q+3]=v.w;
            float4 u = mp[q];
            ma[4*q+0]=u.x; ma[4*q+1]=u.y; ma[4*q+2]=u.z; ma[4*q+3]=u.w;
        }
    }

    // same rank-1 folding: delta[i] = b2[i] + sum_j silu(a_j) * W2T[j][i]
    float acc[H];
    #pragma unroll
    for (int k = 0; k < H; ++k) acc[k] = b2[k];

    #pragma unroll 1
    for (int j = 0; j < H; ++j) {
        const float* wj = W1 + j * 2 * H;
        float a = b1[j];
        #pragma unroll
        for (int k = 0; k < H; ++k) a += hr[k] * wj[k];
        #pragma unroll
        for (int k = 0; k < H; ++k) a += ma[k] * wj[32+k];
        float u = silu(a);
        const float* w2j = W2T + j * H;
        #pragma unroll
        for (int k = 0; k < H; ++k) acc[k] += u * w2j[k];
    }

    {
        float4* ho = (float4*)(h_out + (size_t)n * H);
        #pragma unroll
        for (int q = 0; q < H/4; ++q) {
            float4 v;
            v.x = hr[4*q+0] + acc[4*q+0]; v.y = hr[4*q+1] + acc[4*q+1];
            v.z = hr[4*q+2] + acc[4*q+2]; v.w = hr[4*q+3] + acc[4*q+3];
            ho[q] = v;
        }
    }
}

// ---- output: forces = x @ lin_W.T ------------------------------------------
__global__ __launch_bounds__(256) void out_kernel(
    const float* __restrict__ x, const float* __restrict__ lin,
    float* __restrict__ out, int N)
{
    int n = blockIdx.x * blockDim.x + threadIdx.x;
    if (n >= N) return;
    float xr[DOUT];
    const float4* xp = (const float4*)(x + (size_t)n * DOUT);
    #pragma unroll
    for (int q = 0; q < DOUT/4; ++q) {
        float4 v = xp[q];
        xr[4*q+0]=v.x; xr[4*q+1]=v.y; xr[4*q+2]=v.z; xr[4*q+3]=v.w;
    }
    #pragma unroll
    for (int i = 0; i < 3; ++i) {
        float a = 0.0f;
        #pragma unroll
        for (int k = 0; k < DOUT; ++k) a += xr[k] * lin[i*DOUT+k];
        out[(size_t)n*3+i] = a;
    }
}

extern "C" void kernel_launch(void* const* d_in, const int* in_sizes, int n_in,
                              void* d_out, int out_size, void* d_ws, size_t ws_size,
                              hipStream_t stream) {
    const float* node_attrs = (const float*)d_in[0];
    const float* positions  = (const float*)d_in[1];
    const int*   edge_index = (const int*)d_in[2];
    const float* proj_W   = (const float*)d_in[3];
    const float* emb_in_W = (const float*)d_in[4];
    const float* emb_in_b = (const float*)d_in[5];
    const float* edge_W1  = (const float*)d_in[6];
    const float* edge_b1  = (const float*)d_in[7];
    const float* edge_W2  = (const float*)d_in[8];
    const float* edge_b2  = (const float*)d_in[9];
    const float* node_W1  = (const float*)d_in[10];
    const float* node_b1  = (const float*)d_in[11];
    const float* node_W2  = (const float*)d_in[12];
    const float* node_b2  = (const float*)d_in[13];
    const float* coord_W1 = (const float*)d_in[14];
    const float* coord_b1 = (const float*)d_in[15];
    const float* coord_W2 = (const float*)d_in[16];
    const float* lin_W    = (const float*)d_in[19];

    const int N = in_sizes[0] / 3;
    const int E = in_sizes[2] / 2;
    const int* row = edge_index;
    const int* col = edge_index + E;

    // ws: x0,h0,x1,h1 | xsum(16N), magg(32N) | w2t(2048), nw2t(2048) | ints
    float* x0 = (float*)d_ws;
    float* h0 = x0 + (size_t)DOUT * N;
    float* x1 = h0 + (size_t)H * N;
    float* h1 = x1 + (size_t)DOUT * N;
    float* xsum = h1 + (size_t)H * N;
    float* magg = xsum + (size_t)DOUT * N;
    float* w2t  = magg + (size_t)H * N;
    float* nw2t = w2t + 2 * H * H;
    int* deg    = (int*)(nw2t + 2 * H * H);
    int* startv = deg + N;
    int* cursor = startv + N;
    int* ecol   = cursor + N;

    int nB256 = (N + 255) / 256;
    int eB256 = (E + 255) / 256;
    int egBlocks = ((size_t)N * T + BLK - 1) / BLK;

    zero_deg<<<nB256, 256, 0, stream>>>(deg, N);
    hist_kernel<<<eB256, 256, 0, stream>>>(row, deg, E);
    scan_kernel<<<1, 1024, 0, stream>>>(deg, startv, cursor, N);
    scatter_kernel<<<eB256, 256, 0, stream>>>(row, col, cursor, ecol, E);
    transpose_w2<<<(2*H*H + 255)/256, 256, 0, stream>>>(edge_W2, w2t);
    transpose_w2<<<(2*H*H + 255)/256, 256, 0, stream>>>(node_W2, nw2t);

    init_nodes<<<nB256, 256, 0, stream>>>(node_attrs, positions,
                                          proj_W, emb_in_W, emb_in_b, x0, h0, N);

    const float* xi = x0; const float* hi = h0;
    float* xo = x1; float* ho = h1;
    for (int l = 0; l < 2; ++l) {
        edge_kernel<<<egBlocks, BLK, 0, stream>>>(
            startv, deg, ecol, positions, xi, hi,
            edge_W1 + l * (H * 68), edge_b1 + l * H,
            w2t + l * (H * H),      edge_b2 + l * H,
            coord_W1 + l * (H * H), coord_b1 + l * H,
            coord_W2 + l * H,
            xsum, magg, N);
        node_kernel<<<nB256, 256, 0, stream>>>(
            deg, xi, hi, xsum, magg,
            node_W1 + l * (H * 2 * H), node_b1 + l * H,
            nw2t + l * (H * H),        node_b2 + l * H,
            xo, ho, N);
        const float* tx = xi; xi = xo; xo = (float*)tx;
        const float* th = hi; hi = ho; ho = (float*)th;
    }

    out_kernel<<<nB256, 256, 0, stream>>>(xi, lin_W, (float*)d_out, N);
}

// Round 7
// 1435.583 us; speedup vs baseline: 5.6517x; 1.0138x over previous
//
#include <hip/hip_runtime.h>

#define H 32
#define DOUT 16
#define T 8     // threads per node in edge kernel
#define BLK 256

__device__ __forceinline__ float silu(float v) {
    return v * __builtin_amdgcn_rcpf(1.0f + __expf(-v));
}

// ---- CSR build: deg histogram -> exclusive scan -> scatter reordered col ---
__global__ __launch_bounds__(256) void zero_deg(int* __restrict__ deg, int N) {
    int i = blockIdx.x * blockDim.x + threadIdx.x;
    if (i < N) deg[i] = 0;
}

__global__ __launch_bounds__(256) void hist_kernel(const int* __restrict__ row,
                                                   int* __restrict__ deg, int E) {
    int e = blockIdx.x * blockDim.x + threadIdx.x;
    if (e < E) atomicAdd(&deg[row[e]], 1);
}

// single block of 1024: chunked serial sums + Hillis-Steele scan over partials
__global__ __launch_bounds__(1024) void scan_kernel(const int* __restrict__ deg,
                                                    int* __restrict__ start,
                                                    int* __restrict__ cursor, int N) {
    __shared__ int part[1024];
    int t = threadIdx.x;
    int ch = (N + 1023) >> 10;
    int lo = t * ch, hi = min(lo + ch, N);
    int s = 0;
    for (int i = lo; i < hi; ++i) s += deg[i];
    part[t] = s;
    __syncthreads();
    for (int off = 1; off < 1024; off <<= 1) {
        int v = (t >= off) ? part[t - off] : 0;
        __syncthreads();
        part[t] += v;
        __syncthreads();
    }
    int run = part[t] - s;  // exclusive prefix
    for (int i = lo; i < hi; ++i) {
        start[i] = run; cursor[i] = run;
        run += deg[i];
    }
}

// stores reordered col directly: ecol[slot] = col[e]
__global__ __launch_bounds__(256) void scatter_kernel(const int* __restrict__ row,
                                                      const int* __restrict__ col,
                                                      int* __restrict__ cursor,
                                                      int* __restrict__ ecol, int E) {
    int e = blockIdx.x * blockDim.x + threadIdx.x;
    if (e < E) {
        int p = atomicAdd(&cursor[row[e]], 1);
        ecol[p] = col[e];
    }
}

// ---- transpose edge_W2 (both layers): W2T[l][j][i] = W2[l][i][j] -----------
__global__ __launch_bounds__(256) void transpose_w2(const float* __restrict__ W2,
                                                    float* __restrict__ W2T) {
    int i = blockIdx.x * blockDim.x + threadIdx.x;
    if (i >= 2 * H * H) return;
    int l = i >> 10, r = (i >> 5) & 31, c = i & 31;   // W2[l][r][c]
    W2T[l * H * H + c * H + r] = W2[i];
}

// ---- init: x = pos@projW.T, h = attrs@embW.T + b ---------------------------
__global__ __launch_bounds__(256) void init_nodes(
    const float* __restrict__ node_attrs, const float* __restrict__ positions,
    const float* __restrict__ projW, const float* __restrict__ embW,
    const float* __restrict__ embB,
    float* __restrict__ x, float* __restrict__ h, int N)
{
    int n = blockIdx.x * blockDim.x + threadIdx.x;
    if (n >= N) return;
    float p0 = positions[3*n+0], p1 = positions[3*n+1], p2 = positions[3*n+2];
    #pragma unroll
    for (int i = 0; i < DOUT; ++i)
        x[(size_t)n*DOUT+i] = projW[i*3+0]*p0 + projW[i*3+1]*p1 + projW[i*3+2]*p2;
    float a0 = node_attrs[3*n+0], a1 = node_attrs[3*n+1], a2 = node_attrs[3*n+2];
    #pragma unroll
    for (int j = 0; j < H; ++j)
        h[(size_t)n*H+j] = embB[j] + embW[j*3+0]*a0 + embW[j*3+1]*a1 + embW[j*3+2]*a2;
}

// ---- edge kernel: T threads/node, all-register dataflow, unroll-4 j-loops --
__global__ __launch_bounds__(BLK) void edge_kernel(
    const int* __restrict__ start, const int* __restrict__ deg,
    const int* __restrict__ ecol,
    const float* __restrict__ positions,
    const float* __restrict__ x_in, const float* __restrict__ h_in,
    const float* __restrict__ eW1, const float* __restrict__ eb1,
    const float* __restrict__ W2T, const float* __restrict__ eb2,
    const float* __restrict__ cW1, const float* __restrict__ cb1,
    const float* __restrict__ cW2,
    float* __restrict__ xsum, float* __restrict__ magg, int N)
{
    int gid = blockIdx.x * BLK + threadIdx.x;
    int n = gid >> 3, sub = gid & (T - 1);
    if (n >= N) return;

    int s0 = start[n], dg = deg[n];

    float xr[DOUT];
    {
        const float4* xp = (const float4*)(x_in + (size_t)n * DOUT);
        #pragma unroll
        for (int q = 0; q < DOUT/4; ++q) {
            float4 v = xp[q];
            xr[4*q+0]=v.x; xr[4*q+1]=v.y; xr[4*q+2]=v.z; xr[4*q+3]=v.w;
        }
    }
    float hr[H];
    {
        const float4* hp = (const float4*)(h_in + (size_t)n * H);
        #pragma unroll
        for (int q = 0; q < H/4; ++q) {
            float4 v = hp[q];
            hr[4*q+0]=v.x; hr[4*q+1]=v.y; hr[4*q+2]=v.z; hr[4*q+3]=v.w;
        }
    }
    float pr0 = positions[3*n+0], pr1 = positions[3*n+1], pr2 = positions[3*n+2];

    float xs[DOUT];
    #pragma unroll
    for (int i = 0; i < DOUT; ++i) xs[i] = 0.0f;
    float ma[H];
    #pragma unroll
    for (int k = 0; k < H; ++k) ma[k] = 0.0f;

    for (int i = sub; i < dg; i += T) {
        int c = ecol[s0 + i];

        float cd[DOUT];
        {
            const float4* xc = (const float4*)(x_in + (size_t)c * DOUT);
            #pragma unroll
            for (int q = 0; q < DOUT/4; ++q) {
                float4 v = xc[q];
                cd[4*q+0] = xr[4*q+0]-v.x; cd[4*q+1] = xr[4*q+1]-v.y;
                cd[4*q+2] = xr[4*q+2]-v.z; cd[4*q+3] = xr[4*q+3]-v.w;
            }
        }
        float radial = 0.0f;
        #pragma unroll
        for (int i2 = 0; i2 < DOUT; ++i2) radial += cd[i2] * cd[i2];

        float hc[H];
        {
            const float4* hp = (const float4*)(h_in + (size_t)c * H);
            #pragma unroll
            for (int q = 0; q < H/4; ++q) {
                float4 v = hp[q];
                hc[4*q+0]=v.x; hc[4*q+1]=v.y; hc[4*q+2]=v.z; hc[4*q+3]=v.w;
            }
        }
        float ea0 = pr0 - positions[3*c+0];
        float ea1 = pr1 - positions[3*c+1];
        float ea2 = pr2 - positions[3*c+2];

        // MLP2 accumulators start at bias; MLP1 neuron j does rank-1 update
        float acc[H];
        #pragma unroll
        for (int k = 0; k < H; ++k) acc[k] = eb2[k];

        #pragma unroll 4
        for (int j = 0; j < H; ++j) {
            const float* wj = eW1 + j * 68;
            float a = eb1[j];
            #pragma unroll
            for (int k = 0; k < H; ++k) a += hr[k] * wj[k];
            #pragma unroll
            for (int k = 0; k < H; ++k) a += hc[k] * wj[32+k];
            a += radial * wj[64] + ea0 * wj[65] + ea1 * wj[66] + ea2 * wj[67];
            float m1j = silu(a);
            const float* w2j = W2T + j * H;   // column j of W2
            #pragma unroll
            for (int k = 0; k < H; ++k) acc[k] += m1j * w2j[k];
        }

        // m2 = silu(acc); aggregate
        #pragma unroll
        for (int k = 0; k < H; ++k) {
            float v = silu(acc[k]);
            acc[k] = v;
            ma[k] += v;
        }

        // coord MLP: 32 -> 32 silu -> 1
        float cm = 0.0f;
        #pragma unroll 4
        for (int j = 0; j < H; ++j) {
            const float* wj = cW1 + j * H;
            float a = cb1[j];
            #pragma unroll
            for (int k = 0; k < H; ++k) a += acc[k] * wj[k];
            cm += silu(a) * cW2[j];
        }

        #pragma unroll
        for (int i2 = 0; i2 < DOUT; ++i2) xs[i2] += cd[i2] * cm;
    }

    // reduce partials across the T adjacent lanes of this node (same wave)
    #pragma unroll
    for (int m = 1; m < T; m <<= 1) {
        #pragma unroll
        for (int k = 0; k < H; ++k) ma[k] += __shfl_xor(ma[k], m, 64);
        #pragma unroll
        for (int i = 0; i < DOUT; ++i) xs[i] += __shfl_xor(xs[i], m, 64);
    }

    if (sub == 0) {
        float4* mo = (float4*)(magg + (size_t)n * H);
        #pragma unroll
        for (int q = 0; q < H/4; ++q) {
            float4 v; v.x=ma[4*q+0]; v.y=ma[4*q+1]; v.z=ma[4*q+2]; v.w=ma[4*q+3];
            mo[q] = v;
        }
        float4* xo = (float4*)(xsum + (size_t)n * DOUT);
        #pragma unroll
        for (int q = 0; q < DOUT/4; ++q) {
            float4 v; v.x=xs[4*q+0]; v.y=xs[4*q+1]; v.z=xs[4*q+2]; v.w=xs[4*q+3];
            xo[q] = v;
        }
    }
}

// ---- node update: x += xsum/max(deg,1); h += MLP([h, m_agg]) ---------------
__global__ __launch_bounds__(256) void node_kernel(
    const int* __restrict__ deg,
    const float* __restrict__ x_in, const float* __restrict__ h_in,
    const float* __restrict__ xsum, const float* __restrict__ magg,
    const float* __restrict__ W1, const float* __restrict__ b1,
    const float* __restrict__ W2T, const float* __restrict__ b2,
    float* __restrict__ x_out, float* __restrict__ h_out, int N)
{
    int n = blockIdx.x * blockDim.x + threadIdx.x;
    if (n >= N) return;

    float inv = __builtin_amdgcn_rcpf(fmaxf((float)deg[n], 1.0f));
    {
        const float4* xi = (const float4*)(x_in + (size_t)n * DOUT);
        const float4* xa = (const float4*)(xsum + (size_t)n * DOUT);
        float4* xo = (float4*)(x_out + (size_t)n * DOUT);
        #pragma unroll
        for (int q = 0; q < DOUT/4; ++q) {
            float4 a = xi[q], b = xa[q];
            float4 v; v.x=a.x+b.x*inv; v.y=a.y+b.y*inv; v.z=a.z+b.z*inv; v.w=a.w+b.w*inv;
            xo[q] = v;
        }
    }

    float hr[H], ma[H];
    {
        const float4* hp = (const float4*)(h_in + (size_t)n * H);
        const float4* mp = (const float4*)(magg + (size_t)n * H);
        #pragma unroll
        for (int q = 0; q < H/4; ++q) {
            float4 v = hp[q];
            hr[4*q+0]=v.x; hr[4*q+1]=v.y; hr[4*q+2]=v.z; hr[4*q+3]=v.w;
            float4 u = mp[q];
            ma[4*q+0]=u.x; ma[4*q+1]=u.y; ma[4*q+2]=u.z; ma[4*q+3]=u.w;
        }
    }

    // rank-1 folding: delta[i] = b2[i] + sum_j silu(a_j) * W2T[j][i]
    float acc[H];
    #pragma unroll
    for (int k = 0; k < H; ++k) acc[k] = b2[k];

    #pragma unroll 4
    for (int j = 0; j < H; ++j) {
        const float* wj = W1 + j * 2 * H;
        float a = b1[j];
        #pragma unroll
        for (int k = 0; k < H; ++k) a += hr[k] * wj[k];
        #pragma unroll
        for (int k = 0; k < H; ++k) a += ma[k] * wj[32+k];
        float u = silu(a);
        const float* w2j = W2T + j * H;
        #pragma unroll
        for (int k = 0; k < H; ++k) acc[k] += u * w2j[k];
    }

    {
        float4* ho = (float4*)(h_out + (size_t)n * H);
        #pragma unroll
        for (int q = 0; q < H/4; ++q) {
            float4 v;
            v.x = hr[4*q+0] + acc[4*q+0]; v.y = hr[4*q+1] + acc[4*q+1];
            v.z = hr[4*q+2] + acc[4*q+2]; v.w = hr[4*q+3] + acc[4*q+3];
            ho[q] = v;
        }
    }
}

// ---- output: forces = x @ lin_W.T ------------------------------------------
__global__ __launch_bounds__(256) void out_kernel(
    const float* __restrict__ x, const float* __restrict__ lin,
    float* __restrict__ out, int N)
{
    int n = blockIdx.x * blockDim.x + threadIdx.x;
    if (n >= N) return;
    float xr[DOUT];
    const float4* xp = (const float4*)(x + (size_t)n * DOUT);
    #pragma unroll
    for (int q = 0; q < DOUT/4; ++q) {
        float4 v = xp[q];
        xr[4*q+0]=v.x; xr[4*q+1]=v.y; xr[4*q+2]=v.z; xr[4*q+3]=v.w;
    }
    #pragma unroll
    for (int i = 0; i < 3; ++i) {
        float a = 0.0f;
        #pragma unroll
        for (int k = 0; k < DOUT; ++k) a += xr[k] * lin[i*DOUT+k];
        out[(size_t)n*3+i] = a;
    }
}

extern "C" void kernel_launch(void* const* d_in, const int* in_sizes, int n_in,
                              void* d_out, int out_size, void* d_ws, size_t ws_size,
                              hipStream_t stream) {
    const float* node_attrs = (const float*)d_in[0];
    const float* positions  = (const float*)d_in[1];
    const int*   edge_index = (const int*)d_in[2];
    const float* proj_W   = (const float*)d_in[3];
    const float* emb_in_W = (const float*)d_in[4];
    const float* emb_in_b = (const float*)d_in[5];
    const float* edge_W1  = (const float*)d_in[6];
    const float* edge_b1  = (const float*)d_in[7];
    const float* edge_W2  = (const float*)d_in[8];
    const float* edge_b2  = (const float*)d_in[9];
    const float* node_W1  = (const float*)d_in[10];
    const float* node_b1  = (const float*)d_in[11];
    const float* node_W2  = (const float*)d_in[12];
    const float* node_b2  = (const float*)d_in[13];
    const float* coord_W1 = (const float*)d_in[14];
    const float* coord_b1 = (const float*)d_in[15];
    const float* coord_W2 = (const float*)d_in[16];
    const float* lin_W    = (const float*)d_in[19];

    const int N = in_sizes[0] / 3;
    const int E = in_sizes[2] / 2;
    const int* row = edge_index;
    const int* col = edge_index + E;

    // ws: x0,h0,x1,h1 | xsum(16N), magg(32N) | w2t(2048), nw2t(2048) | ints
    float* x0 = (float*)d_ws;
    float* h0 = x0 + (size_t)DOUT * N;
    float* x1 = h0 + (size_t)H * N;
    float* h1 = x1 + (size_t)DOUT * N;
    float* xsum = h1 + (size_t)H * N;
    float* magg = xsum + (size_t)DOUT * N;
    float* w2t  = magg + (size_t)H * N;
    float* nw2t = w2t + 2 * H * H;
    int* deg    = (int*)(nw2t + 2 * H * H);
    int* startv = deg + N;
    int* cursor = startv + N;
    int* ecol   = cursor + N;

    int nB256 = (N + 255) / 256;
    int eB256 = (E + 255) / 256;
    int egBlocks = ((size_t)N * T + BLK - 1) / BLK;

    zero_deg<<<nB256, 256, 0, stream>>>(deg, N);
    hist_kernel<<<eB256, 256, 0, stream>>>(row, deg, E);
    scan_kernel<<<1, 1024, 0, stream>>>(deg, startv, cursor, N);
    scatter_kernel<<<eB256, 256, 0, stream>>>(row, col, cursor, ecol, E);
    transpose_w2<<<(2*H*H + 255)/256, 256, 0, stream>>>(edge_W2, w2t);
    transpose_w2<<<(2*H*H + 255)/256, 256, 0, stream>>>(node_W2, nw2t);

    init_nodes<<<nB256, 256, 0, stream>>>(node_attrs, positions,
                                          proj_W, emb_in_W, emb_in_b, x0, h0, N);

    const float* xi = x0; const float* hi = h0;
    float* xo = x1; float* ho = h1;
    for (int l = 0; l < 2; ++l) {
        edge_kernel<<<egBlocks, BLK, 0, stream>>>(
            startv, deg, ecol, positions, xi, hi,
            edge_W1 + l * (H * 68), edge_b1 + l * H,
            w2t + l * (H * H),      edge_b2 + l * H,
            coord_W1 + l * (H * H), coord_b1 + l * H,
            coord_W2 + l * H,
            xsum, magg, N);
        node_kernel<<<nB256, 256, 0, stream>>>(
            deg, xi, hi, xsum, magg,
            node_W1 + l * (H * 2 * H), node_b1 + l * H,
            nw2t + l * (H * H),        node_b2 + l * H,
            xo, ho, N);
        const float* tx = xi; xi = xo; xo = (float*)tx;
        const float* th = hi; hi = ho; ho = (float*)th;
    }

    out_kernel<<<nB256, 256, 0, stream>>>(xi, lin_W, (float*)d_out, N);
}